// Round 13
// baseline (108.104 us; speedup 1.0000x reference)
//
#include <hip/hip_runtime.h>
#include <hip/hip_bf16.h>
#include <stdint.h>
#include <stddef.h>

#define S_LEN 2048
#define DMODEL 1024
#define NHEAD 16
#define HDIM 64
#define BATCH 2
#define MROWS (BATCH * S_LEN) /* 4096 */
#define QK_LD 2048            /* qkv buffer holds q|k only */

typedef unsigned short u16;
typedef __attribute__((ext_vector_type(8))) short bf16x8;
typedef __attribute__((ext_vector_type(4))) short bf16x4;
typedef __attribute__((ext_vector_type(4))) float f32x4;

__device__ inline u16 f32_to_bf16(float f) {
  union { float f; unsigned int u; } v; v.f = f;
  unsigned int u = v.u;
  unsigned int r = (u + 0x7fffu + ((u >> 16) & 1u)) >> 16;
  return (u16)r;
}

__device__ inline void gload16(const u16* g, u16* l) {
  __builtin_amdgcn_global_load_lds(
      (const __attribute__((address_space(1))) unsigned int*)g,
      (__attribute__((address_space(3))) unsigned int*)l, 16, 0, 0);
}

// ---------------- fused prologue: conv + window + W-transpose ----------------
__global__ __launch_bounds__(256) void prep(const float* __restrict__ x, u16* __restrict__ xb,
                                            const float* __restrict__ alpha, int* __restrict__ halfw,
                                            const float* __restrict__ Wq, const float* __restrict__ Wk,
                                            const float* __restrict__ Wv, u16* __restrict__ Wt) {
  __shared__ float lds[32 * 33]; // 4224 B
  const int bid = blockIdx.x, tid = threadIdx.x;

  if (bid < 2048) {
    size_t i = ((size_t)bid * 256 + tid) * 8;
    float4 v0 = *(const float4*)(x + i);
    float4 v1 = *(const float4*)(x + i + 4);
    bf16x8 r;
    r[0] = (short)f32_to_bf16(v0.x); r[1] = (short)f32_to_bf16(v0.y);
    r[2] = (short)f32_to_bf16(v0.z); r[3] = (short)f32_to_bf16(v0.w);
    r[4] = (short)f32_to_bf16(v1.x); r[5] = (short)f32_to_bf16(v1.y);
    r[6] = (short)f32_to_bf16(v1.z); r[7] = (short)f32_to_bf16(v1.w);
    *(bf16x8*)(xb + i) = r;
  } else if (bid == 2048) {
    float s = 0.f;
    for (int i = tid; i < BATCH * DMODEL; i += 256) {
      int b = i >> 10, d = i & 1023;
      size_t base = (size_t)b * S_LEN * DMODEL + d;
      float f1 = x[base + (size_t)(S_LEN - 1) * DMODEL];
      float f0 = x[base + (size_t)(S_LEN - 2) * DMODEL];
      s += fabsf(f1 - f0);
    }
#pragma unroll
    for (int m = 32; m >= 1; m >>= 1) s += __shfl_xor(s, m, 64);
    if ((tid & 63) == 0) lds[tid >> 6] = s;
    __syncthreads();
    if (tid == 0) {
      float total = lds[0] + lds[1] + lds[2] + lds[3];
      float mean = total / (float)(BATCH * DMODEL);
      float e1 = x[(size_t)(S_LEN - 1) * DMODEL];
      float e0 = x[(size_t)(S_LEN - 2) * DMODEL];
      float ew = fabsf(e1 - e0);
      float a = 1.f / (1.f + expf(-alpha[0]));
      float sig = a * mean + (1.f - a) * ew;
      float scale = 1.f / (1.f + expf(-sig));
      int wv = (int)floorf(24.f + 96.f * scale);
      *halfw = wv >> 1;
    }
  } else {
    float (*tile)[33] = (float (*)[33])lds;
    const int r = bid - 2049;
    const int z = r >> 10, rem = r & 1023;
    const int k0 = (rem >> 5) * 32, n0 = (rem & 31) * 32;
    const float* W = z == 0 ? Wq : (z == 1 ? Wk : Wv);
    const int tx = tid & 31, ty = tid >> 5;
#pragma unroll
    for (int i = 0; i < 4; ++i)
      tile[ty + i * 8][tx] = W[(size_t)(k0 + ty + i * 8) * DMODEL + n0 + tx];
    __syncthreads();
    u16* o = Wt + (size_t)z * DMODEL * DMODEL;
#pragma unroll
    for (int i = 0; i < 4; ++i)
      o[(size_t)(n0 + ty + i * 8) * DMODEL + k0 + tx] = f32_to_bf16(tile[tx][ty + i * 8]);
  }
}

// ---------------- Wc = blockdiag(W_o) @ Wfc, stored transposed bf16 [N][K] ----------------
__global__ __launch_bounds__(128) void build_wc(const float* __restrict__ W_o,
                                                const float* __restrict__ Wfc,
                                                u16* __restrict__ Wc_t) {
  __shared__ float lds[64 * 128];
  int nb = blockIdx.x, h = blockIdx.y, tx = threadIdx.x;
  int n0 = nb * 128;
#pragma unroll
  for (int c = 0; c < 64; ++c)
    lds[c * 128 + tx] = Wfc[(size_t)(h * 64 + c) * DMODEL + n0 + tx];
  __syncthreads();
  float acc[64];
#pragma unroll
  for (int d = 0; d < 64; ++d) acc[d] = 0.f;
  for (int c = 0; c < 64; ++c) {
    float wv = lds[c * 128 + tx];
#pragma unroll
    for (int d = 0; d < 64; ++d)
      acc[d] += W_o[(size_t)(h * 64 + d) * 64 + c] * wv;
  }
  u16 tmp[64];
#pragma unroll
  for (int d = 0; d < 64; ++d) tmp[d] = f32_to_bf16(acc[d]);
  u16* dst = Wc_t + (size_t)(n0 + tx) * DMODEL + h * 64;
#pragma unroll
  for (int q = 0; q < 8; ++q)
    *(bf16x8*)(dst + q * 8) = *(bf16x8*)(tmp + q * 8);
}

// ---------------- QKV GEMM: m201-style 256x256, 8 waves, 4 half-tile slots, ----------------
// trickled staging (1 half-tile/phase), counted vmcnt(2) at K-tile boundary only.
// Per tile T (4 phases, 16 MFMA each): stage {(T+1).A1, (T+1).B0, (T+1).B1, (T+2).A0}.
// Wave output = two 64-row strips (m0-3 in A-half0, m4-7 in A-half1) so each phase
// reads exactly one A-half; B-half fixed per wave (wc>>1).
__global__ __launch_bounds__(512, 2) void gemm_qkv(
    const u16* __restrict__ A, const u16* __restrict__ Bt,
    const float* __restrict__ bq, const float* __restrict__ bk,
    const float* __restrict__ bv, u16* __restrict__ out, u16* __restrict__ vt) {
  __shared__ __align__(16) u16 Asl[4][8192]; // 4 half-tile slots [128][64]
  __shared__ __align__(16) u16 Bsl[4][8192];

  const int tid = threadIdx.x;
  const int l = tid & 63, w = tid >> 6;   // 8 waves
  const int wr = w >> 2, wc = w & 3;      // 2 M-groups x 4 N-groups
  const int lrow = l & 15, lk = l >> 4;
  const int bh = wc >> 1, brow0 = (wc & 1) * 64;

  // XCD swizzle: grid 192 = 8 x 24; per XCD 4 bm x 6 bn
  const int xcd = blockIdx.x & 7;
  const int idx = blockIdx.x >> 3;        // 0..23
  const int bm = (xcd >> 1) * 4 + (idx & 3);
  const int bn = (xcd & 1) * 6 + (idx >> 2);
  const int rowA0 = bm * 256, colB0 = bn * 256;

  f32x4 acc[8][4] = {};

  auto stageA = [&](int t, int h) {   // one A half-tile: 2 gloads/thread
    u16* dst = Asl[(2 * t + h) & 3];
    const int kt = t * 64;
#pragma unroll
    for (int i2 = 0; i2 < 2; ++i2) {
      int c = i2 * 512 + tid;
      int row = c >> 3, u = c & 7;
      const u16* g = A + (size_t)(rowA0 + h * 128 + row) * DMODEL + kt + ((u ^ (row & 7)) << 3);
      gload16(g, dst + c * 8);
    }
  };
  auto stageB = [&](int t, int h) {
    u16* dst = Bsl[(2 * t + h) & 3];
    const int kt = t * 64;
#pragma unroll
    for (int i2 = 0; i2 < 2; ++i2) {
      int c = i2 * 512 + tid;
      int row = c >> 3, u = c & 7;
      const u16* g = Bt + (size_t)(colB0 + h * 128 + row) * DMODEL + kt + ((u ^ (row & 7)) << 3);
      gload16(g, dst + c * 8);
    }
  };

  // prologue: tile0 complete + tile1.A0; drain to 2 outstanding (t1.A0 in flight)
  stageA(0, 0); stageA(0, 1); stageB(0, 0); stageB(0, 1); stageA(1, 0);
  asm volatile("s_waitcnt vmcnt(2)" ::: "memory");
  __builtin_amdgcn_s_barrier();

#pragma unroll 1
  for (int T = 0; T < 16; ++T) {
    const u16* Bs_ = Bsl[(2 * T + bh) & 3];
    const u16* As0 = Asl[(2 * T) & 3];
    const u16* As1 = Asl[(2 * T + 1) & 3];
    bf16x8 bg[4], af[4];

    // ---- phase 1: kk0, m0-3 (+bg kk0) ; stage (T+1).A1 ----
#pragma unroll
    for (int n = 0; n < 4; ++n) {
      int r = brow0 + n * 16 + lrow;
      bg[n] = *(const bf16x8*)(Bs_ + r * 64 + ((lk ^ (r & 7)) << 3));
    }
#pragma unroll
    for (int mi = 0; mi < 4; ++mi) {
      int r = wr * 64 + mi * 16 + lrow;
      af[mi] = *(const bf16x8*)(As0 + r * 64 + ((lk ^ (r & 7)) << 3));
    }
    if (T + 1 < 16) stageA(T + 1, 1);
    __builtin_amdgcn_s_barrier();
    asm volatile("s_waitcnt lgkmcnt(0)" ::: "memory");
    __builtin_amdgcn_sched_barrier(0);
    __builtin_amdgcn_s_setprio(1);
#pragma unroll
    for (int mi = 0; mi < 4; ++mi)
#pragma unroll
      for (int n = 0; n < 4; ++n)
        acc[mi][n] = __builtin_amdgcn_mfma_f32_16x16x32_bf16(af[mi], bg[n], acc[mi][n], 0, 0, 0);
    __builtin_amdgcn_s_setprio(0);
    __builtin_amdgcn_s_barrier();

    // ---- phase 2: kk0, m4-7 (bg reuse) ; stage (T+1).B0 ----
#pragma unroll
    for (int mi = 0; mi < 4; ++mi) {
      int r = wr * 64 + mi * 16 + lrow;
      af[mi] = *(const bf16x8*)(As1 + r * 64 + ((lk ^ (r & 7)) << 3));
    }
    if (T + 1 < 16) stageB(T + 1, 0);
    __builtin_amdgcn_s_barrier();
    asm volatile("s_waitcnt lgkmcnt(0)" ::: "memory");
    __builtin_amdgcn_sched_barrier(0);
    __builtin_amdgcn_s_setprio(1);
#pragma unroll
    for (int mi = 0; mi < 4; ++mi)
#pragma unroll
      for (int n = 0; n < 4; ++n)
        acc[4 + mi][n] = __builtin_amdgcn_mfma_f32_16x16x32_bf16(af[mi], bg[n], acc[4 + mi][n], 0, 0, 0);
    __builtin_amdgcn_s_setprio(0);
    __builtin_amdgcn_s_barrier();

    // ---- phase 3: kk1, m0-3 (+bg kk1) ; stage (T+1).B1 ----
#pragma unroll
    for (int n = 0; n < 4; ++n) {
      int r = brow0 + n * 16 + lrow;
      bg[n] = *(const bf16x8*)(Bs_ + r * 64 + (((4 + lk) ^ (r & 7)) << 3));
    }
#pragma unroll
    for (int mi = 0; mi < 4; ++mi) {
      int r = wr * 64 + mi * 16 + lrow;
      af[mi] = *(const bf16x8*)(As0 + r * 64 + (((4 + lk) ^ (r & 7)) << 3));
    }
    if (T + 1 < 16) stageB(T + 1, 1);
    __builtin_amdgcn_s_barrier();
    asm volatile("s_waitcnt lgkmcnt(0)" ::: "memory");
    __builtin_amdgcn_sched_barrier(0);
    __builtin_amdgcn_s_setprio(1);
#pragma unroll
    for (int mi = 0; mi < 4; ++mi)
#pragma unroll
      for (int n = 0; n < 4; ++n)
        acc[mi][n] = __builtin_amdgcn_mfma_f32_16x16x32_bf16(af[mi], bg[n], acc[mi][n], 0, 0, 0);
    __builtin_amdgcn_s_setprio(0);
    __builtin_amdgcn_s_barrier();

    // ---- phase 4: kk1, m4-7 ; stage (T+2).A0 ; counted vmcnt ----
#pragma unroll
    for (int mi = 0; mi < 4; ++mi) {
      int r = wr * 64 + mi * 16 + lrow;
      af[mi] = *(const bf16x8*)(As1 + r * 64 + (((4 + lk) ^ (r & 7)) << 3));
    }
    if (T + 2 < 16) {
      stageA(T + 2, 0);
      asm volatile("s_waitcnt vmcnt(2)" ::: "memory");  // next tile landed; newest half in flight
    } else {
      asm volatile("s_waitcnt vmcnt(0)" ::: "memory");  // tail drain
    }
    __builtin_amdgcn_s_barrier();
    asm volatile("s_waitcnt lgkmcnt(0)" ::: "memory");
    __builtin_amdgcn_sched_barrier(0);
    __builtin_amdgcn_s_setprio(1);
#pragma unroll
    for (int mi = 0; mi < 4; ++mi)
#pragma unroll
      for (int n = 0; n < 4; ++n)
        acc[4 + mi][n] = __builtin_amdgcn_mfma_f32_16x16x32_bf16(af[mi], bg[n], acc[4 + mi][n], 0, 0, 0);
    __builtin_amdgcn_s_setprio(0);
    __builtin_amdgcn_s_barrier();
  }

  // ---- epilogue: block is entirely q, k, or v (colB0 multiple of 256) ----
#pragma unroll
  for (int n = 0; n < 4; ++n) {
    int c = colB0 + wc * 64 + n * 16 + lrow;   // 0..3071
    if (colB0 < 1024) {        // q (scale 1/8 fold)
      float bias = bq[c];
#pragma unroll
      for (int m = 0; m < 8; ++m) {
        int r0 = rowA0 + ((m >> 2) << 7) + wr * 64 + (m & 3) * 16 + lk * 4;
#pragma unroll
        for (int j = 0; j < 4; ++j)
          out[(size_t)(r0 + j) * QK_LD + c] = f32_to_bf16((acc[m][n][j] + bias) * 0.125f);
      }
    } else if (colB0 < 2048) { // k
      float bias = bk[c - 1024];
#pragma unroll
      for (int m = 0; m < 8; ++m) {
        int r0 = rowA0 + ((m >> 2) << 7) + wr * 64 + (m & 3) * 16 + lk * 4;
#pragma unroll
        for (int j = 0; j < 4; ++j)
          out[(size_t)(r0 + j) * QK_LD + c] = f32_to_bf16(acc[m][n][j] + bias);
      }
    } else {                    // v -> vT[b][d][s]
      int dfull = c - 2048;
      float bias = bv[dfull];
#pragma unroll
      for (int m = 0; m < 8; ++m) {
        int r0 = rowA0 + ((m >> 2) << 7) + wr * 64 + (m & 3) * 16 + lk * 4;
        int bb = r0 >> 11, s = r0 & 2047;
        bf16x4 p;
#pragma unroll
        for (int j = 0; j < 4; ++j) p[j] = (short)f32_to_bf16(acc[m][n][j] + bias);
        *(bf16x4*)(vt + ((size_t)bb << 21) + (size_t)dfull * 2048 + s) = p;
      }
    }
  }
}

// ---------------- final FC GEMM: 64x128 tile, single 24KB buffer, 2 blocks/CU ----------------
__global__ __launch_bounds__(256, 2) void gemm_fc(const u16* __restrict__ A,
                                                  const u16* __restrict__ Bt,
                                                  const float* __restrict__ bias,
                                                  float* __restrict__ out) {
  __shared__ __align__(16) u16 smem[(64 + 128) * 64]; // 24 KiB: A | B

  const int tid = threadIdx.x;
  const int l = tid & 63, w = tid >> 6;
  const int wr = w >> 1, wc = w & 1;      // wave tile 32 x 64
  const int lrow = l & 15, lk = l >> 4;

  const int bn = blockIdx.x & 7;
  const int bm = blockIdx.x >> 3;         // 0..63
  const int rowA0 = bm * 64, colB0 = bn * 128;

  f32x4 acc[2][4] = {};
  u16* As = smem;
  u16* Bs = smem + 64 * 64;

#pragma unroll 1
  for (int t = 0; t < 16; ++t) {
    const int kt = t * 64;
#pragma unroll
    for (int i = 0; i < 2; ++i) {
      int c = i * 256 + tid;
      int row = c >> 3, u = c & 7;
      const u16* g = A + (size_t)(rowA0 + row) * DMODEL + kt + ((u ^ (row & 7)) << 3);
      gload16(g, As + c * 8);
    }
#pragma unroll
    for (int i = 0; i < 4; ++i) {
      int c = i * 256 + tid;
      int row = c >> 3, u = c & 7;
      const u16* g = Bt + (size_t)(colB0 + row) * DMODEL + kt + ((u ^ (row & 7)) << 3);
      gload16(g, Bs + c * 8);
    }
    asm volatile("s_waitcnt vmcnt(0)");
    __syncthreads();
#pragma unroll
    for (int kk = 0; kk < 2; ++kk) {
      const int swz = ((((kk << 2) + lk) ^ (lrow & 7)) << 3);
      bf16x8 af[2], bg[4];
#pragma unroll
      for (int m = 0; m < 2; ++m)
        af[m] = *(const bf16x8*)(As + (wr * 32 + m * 16 + lrow) * 64 + swz);
#pragma unroll
      for (int n = 0; n < 4; ++n)
        bg[n] = *(const bf16x8*)(Bs + (wc * 64 + n * 16 + lrow) * 64 + swz);
#pragma unroll
      for (int m = 0; m < 2; ++m)
#pragma unroll
        for (int n = 0; n < 4; ++n)
          acc[m][n] = __builtin_amdgcn_mfma_f32_16x16x32_bf16(af[m], bg[n], acc[m][n], 0, 0, 0);
    }
    __syncthreads();
  }

#pragma unroll
  for (int n = 0; n < 4; ++n) {
    int c = colB0 + wc * 64 + n * 16 + lrow;
    float bv = bias[c];
#pragma unroll
    for (int m = 0; m < 2; ++m) {
      int r0 = rowA0 + wr * 32 + m * 16 + lk * 4;
#pragma unroll
      for (int j = 0; j < 4; ++j)
        out[(size_t)(r0 + j) * DMODEL + c] = acc[m][n][j] + bv;
    }
  }
}

// ---------------- banded attention: 64 q x 192 keys; V via pre-transposed vT ----------------
__global__ __launch_bounds__(256) void attn_win(const u16* __restrict__ qkv,
                                                const u16* __restrict__ vt,
                                                u16* __restrict__ ao,
                                                const int* __restrict__ halfptr) {
  __shared__ __align__(16) u16 KP[12800];  // K [192][64] swizzled; reused as P [64][200]
  __shared__ __align__(16) u16 Vs[12800];  // V^T [64 d][200 key-padded]
  const int tid = threadIdx.x, l = tid & 63, w = tid >> 6;
  const int lrow = l & 15, lk = l >> 4;
  const int q0 = blockIdx.x * 64, k0 = q0 - 64;
  const int h = blockIdx.y, b = blockIdx.z;
  const int halfw = *halfptr;
  const int f_lo = (64 - halfw) >> 4;
  const int f_hi = (127 + halfw) >> 4;

  const u16* qb = qkv;
  const u16* kb = qkv + 1024;

#pragma unroll
  for (int i = 0; i < 6; ++i) {
    int c = i * 256 + tid;
    int row = c >> 3, u = c & 7;
    const u16* g = kb + (ptrdiff_t)((b * S_LEN + k0 + row) * QK_LD + h * 64 + ((u ^ (row & 7)) << 3));
    gload16(g, KP + c * 8);
  }
  const int qrow = q0 + w * 16 + lrow;
  bf16x8 qf[2];
#pragma unroll
  for (int kk = 0; kk < 2; ++kk)
    qf[kk] = *(const bf16x8*)(qb + (ptrdiff_t)((b * S_LEN + qrow) * QK_LD + h * 64 + kk * 32 + lk * 8));
#pragma unroll
  for (int i = 0; i < 6; ++i) {
    int o = i * 256 + tid;
    int d = o / 25, ch = o - d * 25;
    int kc = k0 + ch * 8;
    kc = kc < 0 ? 0 : (kc > 2040 ? 2040 : kc);
    const u16* g = vt + ((size_t)b << 21) + (size_t)(h * 64 + d) * 2048 + kc;
    gload16(g, Vs + o * 8);
  }
  {
    int o = 1536 + tid;
    if (o < 1600) {
      int d = o / 25, ch = o - d * 25;
      int kc = k0 + ch * 8;
      kc = kc < 0 ? 0 : (kc > 2040 ? 2040 : kc);
      const u16* g = vt + ((size_t)b << 21) + (size_t)(h * 64 + d) * 2048 + kc;
      gload16(g, Vs + o * 8);
    }
  }

  asm volatile("s_waitcnt vmcnt(6)" ::: "memory");
  __builtin_amdgcn_s_barrier();
  asm volatile("" ::: "memory");

  f32x4 sc[12];
#pragma unroll
  for (int f = 0; f < 12; ++f) sc[f] = (f32x4){0.f, 0.f, 0.f, 0.f};
#pragma unroll
  for (int kk = 0; kk < 2; ++kk) {
#pragma unroll
    for (int f = 0; f < 12; ++f) {
      if (f >= f_lo && f <= f_hi) {
        bf16x8 kf = *(const bf16x8*)(KP + (f * 16 + lrow) * 64 + ((((kk << 2) + lk) ^ (lrow & 7)) << 3));
        sc[f] = __builtin_amdgcn_mfma_f32_16x16x32_bf16(qf[kk], kf, sc[f], 0, 0, 0);
      }
    }
  }

  float rmax[4] = {-3e38f, -3e38f, -3e38f, -3e38f};
  const int qbase = q0 + w * 16 + lk * 4;
#pragma unroll
  for (int f = 0; f < 12; ++f) {
    if (f < f_lo || f > f_hi) continue;
    int kj = k0 + f * 16 + lrow;
    bool kok = (kj >= 0) && (kj < S_LEN);
#pragma unroll
    for (int j = 0; j < 4; ++j) {
      int qi = qbase + j;
      float v = sc[f][j];
      int dd = qi - kj;
      int ad = dd < 0 ? -dd : dd;
      v = (kok && ad <= halfw) ? v : -1e30f;
      sc[f][j] = v;
      rmax[j] = fmaxf(rmax[j], v);
    }
  }
#pragma unroll
  for (int j = 0; j < 4; ++j) {
    rmax[j] = fmaxf(rmax[j], __shfl_xor(rmax[j], 1, 16));
    rmax[j] = fmaxf(rmax[j], __shfl_xor(rmax[j], 2, 16));
    rmax[j] = fmaxf(rmax[j], __shfl_xor(rmax[j], 4, 16));
    rmax[j] = fmaxf(rmax[j], __shfl_xor(rmax[j], 8, 16));
  }
  float rsum[4] = {0.f, 0.f, 0.f, 0.f};
#pragma unroll
  for (int f = 0; f < 12; ++f) {
    if (f < f_lo || f > f_hi) { sc[f] = (f32x4){0.f, 0.f, 0.f, 0.f}; continue; }
#pragma unroll
    for (int j = 0; j < 4; ++j) {
      float e = __expf(sc[f][j] - rmax[j]);
      sc[f][j] = e;
      rsum[j] += e;
    }
  }
#pragma unroll
  for (int j = 0; j < 4; ++j) {
    rsum[j] += __shfl_xor(rsum[j], 1, 16);
    rsum[j] += __shfl_xor(rsum[j], 2, 16);
    rsum[j] += __shfl_xor(rsum[j], 4, 16);
    rsum[j] += __shfl_xor(rsum[j], 8, 16);
  }
  float rinv[4];
#pragma unroll
  for (int j = 0; j < 4; ++j) rinv[j] = 1.0f / rsum[j];

  __builtin_amdgcn_s_barrier();
  asm volatile("" ::: "memory");

  u16* Ps = KP;
#pragma unroll
  for (int f = 0; f < 12; ++f)
#pragma unroll
    for (int j = 0; j < 4; ++j) {
      int prow = w * 16 + lk * 4 + j;
      Ps[prow * 200 + f * 16 + lrow] = f32_to_bf16(sc[f][j] * rinv[j]);
    }
  asm volatile("s_waitcnt lgkmcnt(0) vmcnt(0)" ::: "memory");
  __builtin_amdgcn_s_barrier();
  asm volatile("" ::: "memory");

  f32x4 o[4] = {};
#pragma unroll
  for (int jt = 0; jt < 6; ++jt) {
    bf16x8 pa = *(const bf16x8*)(Ps + (w * 16 + lrow) * 200 + jt * 32 + lk * 8);
#pragma unroll
    for (int n = 0; n < 4; ++n) {
      bf16x8 vf = *(const bf16x8*)(Vs + (n * 16 + lrow) * 200 + jt * 32 + lk * 8);
      o[n] = __builtin_amdgcn_mfma_f32_16x16x32_bf16(pa, vf, o[n], 0, 0, 0);
    }
  }
#pragma unroll
  for (int n = 0; n < 4; ++n)
#pragma unroll
    for (int j = 0; j < 4; ++j) {
      int qi = q0 + w * 16 + lk * 4 + j;
      int d = n * 16 + lrow;
      ao[(size_t)(b * S_LEN + qi) * DMODEL + h * 64 + d] = f32_to_bf16(o[n][j]);
    }
}

// ---------------- launch ----------------
extern "C" void kernel_launch(void* const* d_in, const int* in_sizes, int n_in,
                              void* d_out, int out_size, void* d_ws, size_t ws_size,
                              hipStream_t stream) {
  (void)in_sizes; (void)n_in; (void)out_size; (void)ws_size;
  const float* x     = (const float*)d_in[0];
  const float* alpha = (const float*)d_in[1];
  const float* Wq    = (const float*)d_in[2];
  const float* bq    = (const float*)d_in[3];
  const float* Wk    = (const float*)d_in[4];
  const float* bk    = (const float*)d_in[5];
  const float* Wv    = (const float*)d_in[6];
  const float* bv    = (const float*)d_in[7];
  const float* W_o   = (const float*)d_in[8];
  const float* Wfc   = (const float*)d_in[9];
  const float* bfc   = (const float*)d_in[10];

  char* ws = (char*)d_ws;
  int* halfw  = (int*)ws;
  u16* xb     = (u16*)(ws + 256);
  u16* Wqkv_t = xb + (size_t)MROWS * DMODEL;
  u16* qkv    = Wqkv_t + (size_t)3 * DMODEL * DMODEL;    // [4096][2048] q|k
  u16* vt     = qkv + (size_t)MROWS * QK_LD;             // [2][1024][2048]
  u16* ao     = vt + (size_t)BATCH * DMODEL * S_LEN;
  u16* Wc_t   = ao + (size_t)MROWS * DMODEL;

  hipLaunchKernelGGL(prep, dim3(5121), dim3(256), 0, stream,
                     x, xb, alpha, halfw, Wq, Wk, Wv, Wqkv_t);
  hipLaunchKernelGGL(build_wc, dim3(8, 16), dim3(128), 0, stream, W_o, Wfc, Wc_t);
  hipLaunchKernelGGL(gemm_qkv, dim3(192), dim3(512), 0, stream,
                     xb, Wqkv_t, bq, bk, bv, qkv, vt);
  hipLaunchKernelGGL(attn_win, dim3(S_LEN / 64, NHEAD, BATCH), dim3(256), 0, stream,
                     qkv, vt, ao, halfw);
  hipLaunchKernelGGL(gemm_fc, dim3(512), dim3(256), 0, stream,
                     ao, Wc_t, bfc, (float*)d_out);
}

// Round 14
// 100.936 us; speedup vs baseline: 1.0710x; 1.0710x over previous
//
#include <hip/hip_runtime.h>
#include <hip/hip_bf16.h>
#include <stdint.h>
#include <stddef.h>

#define S_LEN 2048
#define DMODEL 1024
#define NHEAD 16
#define HDIM 64
#define BATCH 2
#define MROWS (BATCH * S_LEN) /* 4096 */
#define QK_LD 2048            /* qkv buffer holds q|k only */

typedef unsigned short u16;
typedef __attribute__((ext_vector_type(8))) short bf16x8;
typedef __attribute__((ext_vector_type(4))) short bf16x4;
typedef __attribute__((ext_vector_type(4))) float f32x4;

__device__ inline u16 f32_to_bf16(float f) {
  union { float f; unsigned int u; } v; v.f = f;
  unsigned int u = v.u;
  unsigned int r = (u + 0x7fffu + ((u >> 16) & 1u)) >> 16;
  return (u16)r;
}

__device__ inline void gload16(const u16* g, u16* l) {
  __builtin_amdgcn_global_load_lds(
      (const __attribute__((address_space(1))) unsigned int*)g,
      (__attribute__((address_space(3))) unsigned int*)l, 16, 0, 0);
}

// ---------------- fused prologue: conv + window + W-transpose ----------------
__global__ __launch_bounds__(256) void prep(const float* __restrict__ x, u16* __restrict__ xb,
                                            const float* __restrict__ alpha, int* __restrict__ halfw,
                                            const float* __restrict__ Wq, const float* __restrict__ Wk,
                                            const float* __restrict__ Wv, u16* __restrict__ Wt) {
  __shared__ float lds[32 * 33]; // 4224 B
  const int bid = blockIdx.x, tid = threadIdx.x;

  if (bid < 2048) {
    size_t i = ((size_t)bid * 256 + tid) * 8;
    float4 v0 = *(const float4*)(x + i);
    float4 v1 = *(const float4*)(x + i + 4);
    bf16x8 r;
    r[0] = (short)f32_to_bf16(v0.x); r[1] = (short)f32_to_bf16(v0.y);
    r[2] = (short)f32_to_bf16(v0.z); r[3] = (short)f32_to_bf16(v0.w);
    r[4] = (short)f32_to_bf16(v1.x); r[5] = (short)f32_to_bf16(v1.y);
    r[6] = (short)f32_to_bf16(v1.z); r[7] = (short)f32_to_bf16(v1.w);
    *(bf16x8*)(xb + i) = r;
  } else if (bid == 2048) {
    float s = 0.f;
    for (int i = tid; i < BATCH * DMODEL; i += 256) {
      int b = i >> 10, d = i & 1023;
      size_t base = (size_t)b * S_LEN * DMODEL + d;
      float f1 = x[base + (size_t)(S_LEN - 1) * DMODEL];
      float f0 = x[base + (size_t)(S_LEN - 2) * DMODEL];
      s += fabsf(f1 - f0);
    }
#pragma unroll
    for (int m = 32; m >= 1; m >>= 1) s += __shfl_xor(s, m, 64);
    if ((tid & 63) == 0) lds[tid >> 6] = s;
    __syncthreads();
    if (tid == 0) {
      float total = lds[0] + lds[1] + lds[2] + lds[3];
      float mean = total / (float)(BATCH * DMODEL);
      float e1 = x[(size_t)(S_LEN - 1) * DMODEL];
      float e0 = x[(size_t)(S_LEN - 2) * DMODEL];
      float ew = fabsf(e1 - e0);
      float a = 1.f / (1.f + expf(-alpha[0]));
      float sig = a * mean + (1.f - a) * ew;
      float scale = 1.f / (1.f + expf(-sig));
      int wv = (int)floorf(24.f + 96.f * scale);
      *halfw = wv >> 1;
    }
  } else {
    float (*tile)[33] = (float (*)[33])lds;
    const int r = bid - 2049;
    const int z = r >> 10, rem = r & 1023;
    const int k0 = (rem >> 5) * 32, n0 = (rem & 31) * 32;
    const float* W = z == 0 ? Wq : (z == 1 ? Wk : Wv);
    const int tx = tid & 31, ty = tid >> 5;
#pragma unroll
    for (int i = 0; i < 4; ++i)
      tile[ty + i * 8][tx] = W[(size_t)(k0 + ty + i * 8) * DMODEL + n0 + tx];
    __syncthreads();
    u16* o = Wt + (size_t)z * DMODEL * DMODEL;
#pragma unroll
    for (int i = 0; i < 4; ++i)
      o[(size_t)(n0 + ty + i * 8) * DMODEL + k0 + tx] = f32_to_bf16(tile[tx][ty + i * 8]);
  }
}

// ---------------- Wc = blockdiag(W_o) @ Wfc, stored transposed bf16 [N][K] ----------------
__global__ __launch_bounds__(128) void build_wc(const float* __restrict__ W_o,
                                                const float* __restrict__ Wfc,
                                                u16* __restrict__ Wc_t) {
  __shared__ float lds[64 * 128];
  int nb = blockIdx.x, h = blockIdx.y, tx = threadIdx.x;
  int n0 = nb * 128;
#pragma unroll
  for (int c = 0; c < 64; ++c)
    lds[c * 128 + tx] = Wfc[(size_t)(h * 64 + c) * DMODEL + n0 + tx];
  __syncthreads();
  float acc[64];
#pragma unroll
  for (int d = 0; d < 64; ++d) acc[d] = 0.f;
  for (int c = 0; c < 64; ++c) {
    float wv = lds[c * 128 + tx];
#pragma unroll
    for (int d = 0; d < 64; ++d)
      acc[d] += W_o[(size_t)(h * 64 + d) * 64 + c] * wv;
  }
  u16 tmp[64];
#pragma unroll
  for (int d = 0; d < 64; ++d) tmp[d] = f32_to_bf16(acc[d]);
  u16* dst = Wc_t + (size_t)(n0 + tx) * DMODEL + h * 64;
#pragma unroll
  for (int q = 0; q < 8; ++q)
    *(bf16x8*)(dst + q * 8) = *(bf16x8*)(tmp + q * 8);
}

// ---------------- QKV GEMM: m97-faithful 128x128, single 32KB buffer, 3 blocks/CU ----------------
// (R12 config — best measured total. 8 structure variants R2-R13 all pinned 35-44us;
//  this one gave the best aggregate. Hunt closed per rule #10.)
__global__ __launch_bounds__(256, 3) void gemm_qkv(
    const u16* __restrict__ A, const u16* __restrict__ Bt,
    const float* __restrict__ bq, const float* __restrict__ bk,
    const float* __restrict__ bv, u16* __restrict__ out, u16* __restrict__ vt) {
  __shared__ __align__(16) u16 smem[128 * 64 * 2]; // 32 KiB: A | B

  const int tid = threadIdx.x;
  const int l = tid & 63, w = tid >> 6;   // 4 waves, 2x2
  const int wr = w >> 1, wc = w & 1;
  const int lrow = l & 15, lk = l >> 4;

  const int xcd = blockIdx.x & 7;
  const int idx = blockIdx.x >> 3;        // 0..95
  const int bm = idx & 31;
  const int bn = xcd * 3 + (idx >> 5);
  const int rowA0 = bm * 128;
  const int colB0 = bn * 128;

  f32x4 acc[4][4] = {};
  u16* As = smem;
  u16* Bs = smem + 128 * 64;

#pragma unroll 1
  for (int t = 0; t < 16; ++t) {
    const int kt = t * 64;
#pragma unroll
    for (int i = 0; i < 4; ++i) {
      int c = i * 256 + tid;
      int row = c >> 3, u = c & 7;
      const u16* g = A + (size_t)(rowA0 + row) * DMODEL + kt + ((u ^ (row & 7)) << 3);
      gload16(g, As + c * 8);
    }
#pragma unroll
    for (int i = 0; i < 4; ++i) {
      int c = i * 256 + tid;
      int row = c >> 3, u = c & 7;
      const u16* g = Bt + (size_t)(colB0 + row) * DMODEL + kt + ((u ^ (row & 7)) << 3);
      gload16(g, Bs + c * 8);
    }
    asm volatile("s_waitcnt vmcnt(0)");
    __syncthreads();
#pragma unroll
    for (int kk = 0; kk < 2; ++kk) {
      const int swz = ((((kk << 2) + lk) ^ (lrow & 7)) << 3);
      bf16x8 af[4], bg[4];
#pragma unroll
      for (int m = 0; m < 4; ++m)
        af[m] = *(const bf16x8*)(As + (wr * 64 + m * 16 + lrow) * 64 + swz);
#pragma unroll
      for (int n = 0; n < 4; ++n)
        bg[n] = *(const bf16x8*)(Bs + (wc * 64 + n * 16 + lrow) * 64 + swz);
#pragma unroll
      for (int m = 0; m < 4; ++m)
#pragma unroll
        for (int n = 0; n < 4; ++n)
          acc[m][n] = __builtin_amdgcn_mfma_f32_16x16x32_bf16(af[m], bg[n], acc[m][n], 0, 0, 0);
    }
    __syncthreads();
  }

  // epilogue: cols <2048 -> q|k (q scaled 1/8); cols >=2048 -> vT[b][d][s]
#pragma unroll
  for (int n = 0; n < 4; ++n) {
    int c = colB0 + wc * 64 + n * 16 + lrow;   // 0..3071
    if (c < 2048) {
      float bias = (c < 1024) ? bq[c] : bk[c - 1024];
      float mult = (c < 1024) ? 0.125f : 1.0f;
#pragma unroll
      for (int m = 0; m < 4; ++m) {
        int r0 = rowA0 + wr * 64 + m * 16 + lk * 4;
#pragma unroll
        for (int j = 0; j < 4; ++j)
          out[(size_t)(r0 + j) * QK_LD + c] = f32_to_bf16((acc[m][n][j] + bias) * mult);
      }
    } else {
      const int dfull = c - 2048;
      const float bias = bv[dfull];
#pragma unroll
      for (int m = 0; m < 4; ++m) {
        int r0 = rowA0 + wr * 64 + m * 16 + lk * 4;
        int bb = r0 >> 11, s = r0 & 2047;
        bf16x4 p;
#pragma unroll
        for (int j = 0; j < 4; ++j) p[j] = (short)f32_to_bf16(acc[m][n][j] + bias);
        *(bf16x4*)(vt + ((size_t)bb << 21) + (size_t)dfull * 2048 + s) = p;
      }
    }
  }
}

// ---------------- final FC GEMM: 64x128 tile, single 24KB buffer, 2 blocks/CU ----------------
__global__ __launch_bounds__(256, 2) void gemm_fc(const u16* __restrict__ A,
                                                  const u16* __restrict__ Bt,
                                                  const float* __restrict__ bias,
                                                  float* __restrict__ out) {
  __shared__ __align__(16) u16 smem[(64 + 128) * 64]; // 24 KiB: A | B

  const int tid = threadIdx.x;
  const int l = tid & 63, w = tid >> 6;
  const int wr = w >> 1, wc = w & 1;      // wave tile 32x64
  const int lrow = l & 15, lk = l >> 4;

  const int bn = blockIdx.x & 7;
  const int bm = blockIdx.x >> 3;         // 0..63
  const int rowA0 = bm * 64, colB0 = bn * 128;

  f32x4 acc[2][4] = {};
  u16* As = smem;
  u16* Bs = smem + 64 * 64;

#pragma unroll 1
  for (int t = 0; t < 16; ++t) {
    const int kt = t * 64;
#pragma unroll
    for (int i = 0; i < 2; ++i) {
      int c = i * 256 + tid;
      int row = c >> 3, u = c & 7;
      const u16* g = A + (size_t)(rowA0 + row) * DMODEL + kt + ((u ^ (row & 7)) << 3);
      gload16(g, As + c * 8);
    }
#pragma unroll
    for (int i = 0; i < 4; ++i) {
      int c = i * 256 + tid;
      int row = c >> 3, u = c & 7;
      const u16* g = Bt + (size_t)(colB0 + row) * DMODEL + kt + ((u ^ (row & 7)) << 3);
      gload16(g, Bs + c * 8);
    }
    asm volatile("s_waitcnt vmcnt(0)");
    __syncthreads();
#pragma unroll
    for (int kk = 0; kk < 2; ++kk) {
      const int swz = ((((kk << 2) + lk) ^ (lrow & 7)) << 3);
      bf16x8 af[2], bg[4];
#pragma unroll
      for (int m = 0; m < 2; ++m)
        af[m] = *(const bf16x8*)(As + (wr * 32 + m * 16 + lrow) * 64 + swz);
#pragma unroll
      for (int n = 0; n < 4; ++n)
        bg[n] = *(const bf16x8*)(Bs + (wc * 64 + n * 16 + lrow) * 64 + swz);
#pragma unroll
      for (int m = 0; m < 2; ++m)
#pragma unroll
        for (int n = 0; n < 4; ++n)
          acc[m][n] = __builtin_amdgcn_mfma_f32_16x16x32_bf16(af[m], bg[n], acc[m][n], 0, 0, 0);
    }
    __syncthreads();
  }

#pragma unroll
  for (int n = 0; n < 4; ++n) {
    int c = colB0 + wc * 64 + n * 16 + lrow;
    float bv = bias[c];
#pragma unroll
    for (int m = 0; m < 2; ++m) {
      int r0 = rowA0 + wr * 32 + m * 16 + lk * 4;
#pragma unroll
      for (int j = 0; j < 4; ++j)
        out[(size_t)(r0 + j) * DMODEL + c] = acc[m][n][j] + bv;
    }
  }
}

// ---------------- banded attention: swapped-QK softmax ----------------
// QK^T computed as mfma(K_frag, Q_frag): C-layout (col=lane&15, row=lk*4+j) then
// gives col=q, rows=k -> each lane holds 48 scores of ONE query. Row-softmax is
// 48 register ops + 2 shfls (vs 16); P-scatter is 12 packed ds_write_b64 (vs 48 b16).
// Operand reads unchanged (kf rows=lrow already A-frag form; qf at lrow = B-frag).
__global__ __launch_bounds__(256) void attn_win(const u16* __restrict__ qkv,
                                                const u16* __restrict__ vt,
                                                u16* __restrict__ ao,
                                                const int* __restrict__ halfptr) {
  __shared__ __align__(16) u16 KP[12800];  // K [192][64] swizzled; reused as P [64][200]
  __shared__ __align__(16) u16 Vs[12800];  // V^T [64 d][200 key-padded]
  const int tid = threadIdx.x, l = tid & 63, w = tid >> 6;
  const int lrow = l & 15, lk = l >> 4;
  const int q0 = blockIdx.x * 64, k0 = q0 - 64;
  const int h = blockIdx.y, b = blockIdx.z;
  const int halfw = *halfptr;
  const int f_lo = (64 - halfw) >> 4;
  const int f_hi = (127 + halfw) >> 4;

  const u16* qb = qkv;
  const u16* kb = qkv + 1024;

  // --- K stage (6 gloads/thread) ---
#pragma unroll
  for (int i = 0; i < 6; ++i) {
    int c = i * 256 + tid;
    int row = c >> 3, u = c & 7;
    const u16* g = kb + (ptrdiff_t)((b * S_LEN + k0 + row) * QK_LD + h * 64 + ((u ^ (row & 7)) << 3));
    gload16(g, KP + c * 8);
  }
  // --- Q fragments (q pre-scaled by 1/8); B-frag rows = q = q0 + w*16 + lrow ---
  const int qrow = q0 + w * 16 + lrow;
  bf16x8 qf[2];
#pragma unroll
  for (int kk = 0; kk < 2; ++kk)
    qf[kk] = *(const bf16x8*)(qb + (ptrdiff_t)((b * S_LEN + qrow) * QK_LD + h * 64 + kk * 32 + lk * 8));
  // --- V stage into Vs[64][200] ---
#pragma unroll
  for (int i = 0; i < 6; ++i) {
    int o = i * 256 + tid;
    int d = o / 25, ch = o - d * 25;
    int kc = k0 + ch * 8;
    kc = kc < 0 ? 0 : (kc > 2040 ? 2040 : kc);
    const u16* g = vt + ((size_t)b << 21) + (size_t)(h * 64 + d) * 2048 + kc;
    gload16(g, Vs + o * 8);
  }
  {
    int o = 1536 + tid;
    if (o < 1600) {
      int d = o / 25, ch = o - d * 25;
      int kc = k0 + ch * 8;
      kc = kc < 0 ? 0 : (kc > 2040 ? 2040 : kc);
      const u16* g = vt + ((size_t)b << 21) + (size_t)(h * 64 + d) * 2048 + kc;
      gload16(g, Vs + o * 8);
    }
  }

  asm volatile("s_waitcnt vmcnt(6)" ::: "memory");   // K landed; V in flight
  __builtin_amdgcn_s_barrier();
  asm volatile("" ::: "memory");

  // --- swapped QK^T: sc[f][j] = S[k = k0+f*16+lk*4+j][q = qrow] ---
  f32x4 sc[12];
#pragma unroll
  for (int f = 0; f < 12; ++f) sc[f] = (f32x4){0.f, 0.f, 0.f, 0.f};
#pragma unroll
  for (int kk = 0; kk < 2; ++kk) {
#pragma unroll
    for (int f = 0; f < 12; ++f) {
      if (f >= f_lo && f <= f_hi) {
        bf16x8 kf = *(const bf16x8*)(KP + (f * 16 + lrow) * 64 + ((((kk << 2) + lk) ^ (lrow & 7)) << 3));
        sc[f] = __builtin_amdgcn_mfma_f32_16x16x32_bf16(kf, qf[kk], sc[f], 0, 0, 0);
      }
    }
  }

  // --- mask + softmax (one query per lane) ---
  const int qi = qrow;                 // this lane's query row
  float rmax = -3e38f;
#pragma unroll
  for (int f = 0; f < 12; ++f) {
    if (f < f_lo || f > f_hi) continue;
#pragma unroll
    for (int j = 0; j < 4; ++j) {
      int kj = k0 + f * 16 + lk * 4 + j;
      bool kok = (kj >= 0) && (kj < S_LEN);
      int dd = qi - kj;
      int ad = dd < 0 ? -dd : dd;
      float v = (kok && ad <= halfw) ? sc[f][j] : -1e30f;
      sc[f][j] = v;
      rmax = fmaxf(rmax, v);
    }
  }
  rmax = fmaxf(rmax, __shfl_xor(rmax, 16, 64));
  rmax = fmaxf(rmax, __shfl_xor(rmax, 32, 64));
  float rsum = 0.f;
#pragma unroll
  for (int f = 0; f < 12; ++f) {
    if (f < f_lo || f > f_hi) continue;
#pragma unroll
    for (int j = 0; j < 4; ++j) {
      float e = __expf(sc[f][j] - rmax);
      sc[f][j] = e;
      rsum += e;
    }
  }
  rsum += __shfl_xor(rsum, 16, 64);
  rsum += __shfl_xor(rsum, 32, 64);
  const float rinv = 1.0f / rsum;

  __builtin_amdgcn_s_barrier();   // all KP reads done -> reuse as P
  asm volatile("" ::: "memory");

  // --- P write: packed b64, P[q = w*16+lrow][k = f*16+lk*4 .. +3] ---
  u16* Ps = KP;
  const int prow = w * 16 + lrow;
#pragma unroll
  for (int f = 0; f < 12; ++f) {
    bf16x4 p;
    if (f < f_lo || f > f_hi) {
      p[0] = p[1] = p[2] = p[3] = 0;
    } else {
#pragma unroll
      for (int j = 0; j < 4; ++j) p[j] = (short)f32_to_bf16(sc[f][j] * rinv);
    }
    *(bf16x4*)(Ps + prow * 200 + f * 16 + lk * 4) = p;
  }
  asm volatile("s_waitcnt lgkmcnt(0) vmcnt(0)" ::: "memory");  // P written, V landed
  __builtin_amdgcn_s_barrier();
  asm volatile("" ::: "memory");

  // --- P @ V (unchanged: D[q][d], rows P[q][k], rows Vs[d][k]) ---
  f32x4 o[4] = {};
#pragma unroll
  for (int jt = 0; jt < 6; ++jt) {
    bf16x8 pa = *(const bf16x8*)(Ps + (w * 16 + lrow) * 200 + jt * 32 + lk * 8);
#pragma unroll
    for (int n = 0; n < 4; ++n) {
      bf16x8 vf = *(const bf16x8*)(Vs + (n * 16 + lrow) * 200 + jt * 32 + lk * 8);
      o[n] = __builtin_amdgcn_mfma_f32_16x16x32_bf16(pa, vf, o[n], 0, 0, 0);
    }
  }
#pragma unroll
  for (int n = 0; n < 4; ++n)
#pragma unroll
    for (int j = 0; j < 4; ++j) {
      int qi2 = q0 + w * 16 + lk * 4 + j;
      int d = n * 16 + lrow;
      ao[(size_t)(b * S_LEN + qi2) * DMODEL + h * 64 + d] = f32_to_bf16(o[n][j]);
    }
}

// ---------------- launch ----------------
extern "C" void kernel_launch(void* const* d_in, const int* in_sizes, int n_in,
                              void* d_out, int out_size, void* d_ws, size_t ws_size,
                              hipStream_t stream) {
  (void)in_sizes; (void)n_in; (void)out_size; (void)ws_size;
  const float* x     = (const float*)d_in[0];
  const float* alpha = (const float*)d_in[1];
  const float* Wq    = (const float*)d_in[2];
  const float* bq    = (const float*)d_in[3];
  const float* Wk    = (const float*)d_in[4];
  const float* bk    = (const float*)d_in[5];
  const float* Wv    = (const float*)d_in[6];
  const float* bv    = (const float*)d_in[7];
  const float* W_o   = (const float*)d_in[8];
  const float* Wfc   = (const float*)d_in[9];
  const float* bfc   = (const float*)d_in[10];

  char* ws = (char*)d_ws;
  int* halfw  = (int*)ws;
  u16* xb     = (u16*)(ws + 256);
  u16* Wqkv_t = xb + (size_t)MROWS * DMODEL;
  u16* qkv    = Wqkv_t + (size_t)3 * DMODEL * DMODEL;    // [4096][2048] q|k
  u16* vt     = qkv + (size_t)MROWS * QK_LD;             // [2][1024][2048]
  u16* ao     = vt + (size_t)BATCH * DMODEL * S_LEN;
  u16* Wc_t   = ao + (size_t)MROWS * DMODEL;

  hipLaunchKernelGGL(prep, dim3(5121), dim3(256), 0, stream,
                     x, xb, alpha, halfw, Wq, Wk, Wv, Wqkv_t);
  hipLaunchKernelGGL(build_wc, dim3(8, 16), dim3(128), 0, stream, W_o, Wfc, Wc_t);
  hipLaunchKernelGGL(gemm_qkv, dim3(768), dim3(256), 0, stream,
                     xb, Wqkv_t, bq, bk, bv, qkv, vt);
  hipLaunchKernelGGL(attn_win, dim3(S_LEN / 64, NHEAD, BATCH), dim3(256), 0, stream,
                     qkv, vt, ao, halfw);
  hipLaunchKernelGGL(gemm_fc, dim3(512), dim3(256), 0, stream,
                     ao, Wc_t, bfc, (float*)d_out);
}